// Round 1
// baseline (71.365 us; speedup 1.0000x reference)
//
#include <hip/hip_runtime.h>
#include <math.h>

#define S_DIM 1023
#define B_DIM 64
#define I_DIM 1024
#define CTX_DIM 784
#define NWROWS 16   // 2^M buckets

#define LR_C 0.01f
#define WC_C 5.0f
#define LO_C (-6.906754778648554f)
#define HI_C ( 6.906754778648554f)

// ---------------- kernel A: transpose context + bias row ----------------
__global__ __launch_bounds__(256) void prep_kernel(
    const float* __restrict__ context,   // [B, CTX]
    const float* __restrict__ bias,      // [1]
    float* __restrict__ ctxT,            // [CTX, B]
    float* __restrict__ out_logits)      // [B, S+1]
{
    int g = blockIdx.x * 256 + threadIdx.x;      // 0 .. 784*64-1
    int k = g >> 6;
    int b = g & 63;
    ctxT[g] = context[b * CTX_DIM + k];
    if (g < B_DIM) out_logits[(size_t)g * (S_DIM + 1)] = bias[0];
}

// ---------------- kernel B: halfspace hash -> idx[s][b] ----------------
__global__ __launch_bounds__(256) void gln_idx_kernel(
    const float* __restrict__ cm,        // [S, 4, CTX]
    const float* __restrict__ cb,        // [S, 4]
    const float* __restrict__ ctxT,      // [CTX, B]
    int* __restrict__ idx_g)             // [S, B]
{
    __shared__ float cm_lds[4 * CTX_DIM];
    __shared__ float red[1024];
    __shared__ int   bits[256];
    __shared__ float cb_lds[4];

    const int s = blockIdx.x;
    const int t = threadIdx.x;

    for (int j = t; j < 4 * CTX_DIM; j += 256)
        cm_lds[j] = cm[(size_t)s * 4 * CTX_DIM + j];
    if (t < 4) cb_lds[t] = cb[s * 4 + t];
    __syncthreads();

    const int b = t & 63;
    const int w = t >> 6;          // k-quarter
    float a0 = 0.f, a1 = 0.f, a2 = 0.f, a3 = 0.f;
    const int k0 = w * 196;
    #pragma unroll 4
    for (int kk = 0; kk < 196; ++kk) {
        int k = k0 + kk;
        float cv = ctxT[k * 64 + b];            // coalesced across lanes
        a0 += cm_lds[k] * cv;                   // LDS broadcast (wave-uniform k)
        a1 += cm_lds[CTX_DIM + k] * cv;
        a2 += cm_lds[2 * CTX_DIM + k] * cv;
        a3 += cm_lds[3 * CTX_DIM + k] * cv;
    }
    red[w * 256 +   0 + b] = a0;
    red[w * 256 +  64 + b] = a1;
    red[w * 256 + 128 + b] = a2;
    red[w * 256 + 192 + b] = a3;
    __syncthreads();

    {
        int m = t >> 6, bb = t & 63;
        float sum = red[m * 64 + bb] + red[256 + m * 64 + bb]
                  + red[512 + m * 64 + bb] + red[768 + m * 64 + bb];
        bits[t] = (sum > cb_lds[m]) ? 1 : 0;
    }
    __syncthreads();

    if (t < B_DIM) {
        int v = bits[t] + 2 * bits[64 + t] + 4 * bits[128 + t] + 8 * bits[192 + t];
        idx_g[s * B_DIM + t] = v;
    }
}

// ---------------- kernel C: dots + online update ----------------
__global__ __launch_bounds__(256) void gln_main_kernel(
    const float* __restrict__ logit,     // [B, I]
    const float* __restrict__ target,    // [B]
    const float* __restrict__ weights,   // [S, 16, I]
    const int*   __restrict__ idx_g,     // [S, B]
    float* __restrict__ out_logits,      // [B, S+1]
    float* __restrict__ new_weights)     // [S, 16, I]
{
    __shared__ float Wl[NWROWS * I_DIM];   // 64 KB
    __shared__ int   idx_s[B_DIM];
    __shared__ int   lastb[NWROWS];
    __shared__ float coef[B_DIM];

    const int s = blockIdx.x;
    const int t = threadIdx.x;

    // stage weight table for this neuron: 4096 float4
    const float4* wsrc = (const float4*)(weights + (size_t)s * NWROWS * I_DIM);
    float4* wdst = (float4*)Wl;
    #pragma unroll
    for (int j = 0; j < 16; ++j) wdst[t + j * 256] = wsrc[t + j * 256];
    if (t < B_DIM) idx_s[t] = idx_g[s * B_DIM + t];
    __syncthreads();

    if (t < NWROWS) {
        int lb = -1;
        #pragma unroll
        for (int b = 0; b < B_DIM; ++b)
            if (idx_s[b] == t) lb = b;      // last b wins (numpy scatter order)
        lastb[t] = lb;
    }

    const int wv = t >> 6;   // wave id 0..3
    const int ln = t & 63;   // lane

    // each wave: 16 output dots
    for (int bb = 0; bb < 16; ++bb) {
        const int b = wv * 16 + bb;
        const int row = idx_s[b];
        const float4* lg = (const float4*)(logit + (size_t)b * I_DIM);
        const float4* wr = (const float4*)(Wl + row * I_DIM);
        float acc = 0.f;
        #pragma unroll
        for (int j = 0; j < 4; ++j) {
            float4 a  = lg[ln + j * 64];
            float4 w4 = wr[ln + j * 64];
            acc += a.x * w4.x + a.y * w4.y + a.z * w4.z + a.w * w4.w;
        }
        #pragma unroll
        for (int off = 32; off; off >>= 1) acc += __shfl_xor(acc, off, 64);
        if (ln == 0) {
            float o = fminf(fmaxf(acc, LO_C), HI_C);
            out_logits[(size_t)b * (S_DIM + 1) + s + 1] = o;
            float sg = 1.0f / (1.0f + expf(-o));
            coef[b] = LR_C * (sg - target[b]);
        }
    }
    __syncthreads();

    // update: wave wv handles rows wv*4 .. wv*4+3
    for (int rr = 0; rr < 4; ++rr) {
        const int k = wv * 4 + rr;
        const int b = lastb[k];
        const float4* wr = (const float4*)(Wl + k * I_DIM);
        float4* dst = (float4*)(new_weights + ((size_t)s * NWROWS + k) * I_DIM);
        if (b < 0) {
            #pragma unroll
            for (int j = 0; j < 4; ++j) dst[ln + j * 64] = wr[ln + j * 64];
        } else {
            const float c = coef[b];
            const float4* lg = (const float4*)(logit + (size_t)b * I_DIM);
            #pragma unroll
            for (int j = 0; j < 4; ++j) {
                float4 w4 = wr[ln + j * 64];
                float4 a  = lg[ln + j * 64];
                float4 r;
                r.x = fminf(fmaxf(w4.x - c * a.x, -WC_C), WC_C);
                r.y = fminf(fmaxf(w4.y - c * a.y, -WC_C), WC_C);
                r.z = fminf(fmaxf(w4.z - c * a.z, -WC_C), WC_C);
                r.w = fminf(fmaxf(w4.w - c * a.w, -WC_C), WC_C);
                dst[ln + j * 64] = r;
            }
        }
    }
}

extern "C" void kernel_launch(void* const* d_in, const int* in_sizes, int n_in,
                              void* d_out, int out_size, void* d_ws, size_t ws_size,
                              hipStream_t stream) {
    const float* logit   = (const float*)d_in[0];   // [B, I, 1]
    const float* context = (const float*)d_in[1];   // [B, CTX]
    const float* target  = (const float*)d_in[2];   // [B, 1]
    const float* cm      = (const float*)d_in[3];   // [1, S, 4, CTX]
    const float* cb      = (const float*)d_in[4];   // [1, S, 4, 1]
    const float* weights = (const float*)d_in[5];   // [1, S, 16, I]
    const float* bias    = (const float*)d_in[6];   // [1]

    float* out_logits  = (float*)d_out;                       // [B, S+1]
    float* new_weights = out_logits + (size_t)B_DIM * (S_DIM + 1);

    float* ctxT  = (float*)d_ws;                              // [CTX, B]
    int*   idx_g = (int*)((char*)d_ws + (size_t)CTX_DIM * B_DIM * sizeof(float));

    prep_kernel<<<CTX_DIM * B_DIM / 256, 256, 0, stream>>>(context, bias, ctxT, out_logits);
    gln_idx_kernel<<<S_DIM, 256, 0, stream>>>(cm, cb, ctxT, idx_g);
    gln_main_kernel<<<S_DIM, 256, 0, stream>>>(logit, target, weights, idx_g,
                                               out_logits, new_weights);
}

// Round 2
// 68.919 us; speedup vs baseline: 1.0355x; 1.0355x over previous
//
#include <hip/hip_runtime.h>
#include <math.h>

#define S_DIM 1023
#define B_DIM 64
#define I_DIM 1024
#define CTX_DIM 784
#define CTX4 196          // CTX_DIM / 4
#define NWROWS 16         // 2^M buckets

#define LR_C 0.01f
#define WC_C 5.0f
#define LO_C (-6.906754778648554f)
#define HI_C ( 6.906754778648554f)

// ---------------- kernel A: context -> float4-transposed layout + bias row ----------------
// ctxT4[k4][b] = float4(context[b][4k4 .. 4k4+3]);  layout [196][64] of float4
__global__ __launch_bounds__(256) void prep_kernel(
    const float* __restrict__ context,   // [B, CTX]
    const float* __restrict__ bias,      // [1]
    float4* __restrict__ ctxT4,          // [CTX4][B]
    float* __restrict__ out_logits)      // [B, S+1]
{
    int g = blockIdx.x * 256 + threadIdx.x;      // 0 .. 196*64-1
    int k4 = g >> 6;
    int b  = g & 63;
    ctxT4[g] = *(const float4*)(context + (size_t)b * CTX_DIM + k4 * 4);
    if (g < B_DIM) out_logits[(size_t)g * (S_DIM + 1)] = bias[0];
}

// ---------------- kernel B: halfspace hash -> idx[s][b] ----------------
__global__ __launch_bounds__(256) void gln_idx_kernel(
    const float* __restrict__ cm,        // [S, 4, CTX]
    const float* __restrict__ cb,        // [S, 4]
    const float4* __restrict__ ctxT4,    // [CTX4][B]
    int* __restrict__ idx_g)             // [S, B]
{
    __shared__ float4 cm4[4 * CTX4];     // 12544 B
    __shared__ float  red[4][4][64];     // [q][m][b]
    __shared__ int    bits[4][64];
    __shared__ float  cb_lds[4];

    const int s = blockIdx.x;
    const int t = threadIdx.x;

    const float4* src = (const float4*)(cm + (size_t)s * 4 * CTX_DIM);
    for (int j = t; j < 4 * CTX4; j += 256) cm4[j] = src[j];
    if (t < 4) cb_lds[t] = cb[s * 4 + t];
    __syncthreads();

    const int b = t & 63;
    const int q = t >> 6;          // k-quarter
    float a0 = 0.f, a1 = 0.f, a2 = 0.f, a3 = 0.f;
    const int k0 = q * 49;
    #pragma unroll 7
    for (int kk = 0; kk < 49; ++kk) {
        int k4 = k0 + kk;
        float4 c4 = ctxT4[k4 * 64 + b];          // 16B/lane coalesced
        float4 m0 = cm4[k4];                     // wave-uniform -> LDS broadcast
        float4 m1 = cm4[CTX4 + k4];
        float4 m2 = cm4[2 * CTX4 + k4];
        float4 m3 = cm4[3 * CTX4 + k4];
        a0 += m0.x * c4.x + m0.y * c4.y + m0.z * c4.z + m0.w * c4.w;
        a1 += m1.x * c4.x + m1.y * c4.y + m1.z * c4.z + m1.w * c4.w;
        a2 += m2.x * c4.x + m2.y * c4.y + m2.z * c4.z + m2.w * c4.w;
        a3 += m3.x * c4.x + m3.y * c4.y + m3.z * c4.z + m3.w * c4.w;
    }
    red[q][0][b] = a0;
    red[q][1][b] = a1;
    red[q][2][b] = a2;
    red[q][3][b] = a3;
    __syncthreads();

    {
        int m = t >> 6, bb = t & 63;
        float sum = red[0][m][bb] + red[1][m][bb] + red[2][m][bb] + red[3][m][bb];
        bits[m][bb] = (sum > cb_lds[m]) ? 1 : 0;
    }
    __syncthreads();

    if (t < B_DIM)
        idx_g[s * B_DIM + t] = bits[0][t] + 2 * bits[1][t] + 4 * bits[2][t] + 8 * bits[3][t];
}

// ---------------- kernel C: dots + online update (no LDS weight stage) ----------------
__global__ __launch_bounds__(256) void gln_main2_kernel(
    const float* __restrict__ logit,     // [B, I]
    const float* __restrict__ target,    // [B]
    const float* __restrict__ weights,   // [S, 16, I]
    const int*   __restrict__ idx_g,     // [S, B]
    float* __restrict__ out_logits,      // [B, S+1]
    float* __restrict__ new_weights)     // [S, 16, I]
{
    __shared__ int   idx_s[B_DIM];
    __shared__ int   lastb[NWROWS];
    __shared__ float coef[B_DIM];

    const int s = blockIdx.x;
    const int t = threadIdx.x;
    const int wv = t >> 6;   // wave id 0..3
    const int ln = t & 63;   // lane

    if (t < B_DIM) idx_s[t] = idx_g[s * B_DIM + t];
    __syncthreads();

    if (t < NWROWS) {
        int lb = -1;
        #pragma unroll
        for (int b = 0; b < B_DIM; ++b)
            if (idx_s[b] == t) lb = b;      // last b wins (numpy scatter order)
        lastb[t] = lb;
    }

    const float4* WS = (const float4*)(weights + (size_t)s * NWROWS * I_DIM);

    // phase 1: each wave computes 16 dots, weights straight from global (L1/L2)
    #pragma unroll 2
    for (int bb = 0; bb < 16; ++bb) {
        const int b = wv * 16 + bb;
        const int row = idx_s[b];
        const float4* lg = (const float4*)(logit + (size_t)b * I_DIM);
        const float4* wr = WS + row * (I_DIM / 4);
        float acc = 0.f;
        #pragma unroll
        for (int j = 0; j < 4; ++j) {
            float4 a  = lg[ln + j * 64];
            float4 w4 = wr[ln + j * 64];
            acc += a.x * w4.x + a.y * w4.y + a.z * w4.z + a.w * w4.w;
        }
        #pragma unroll
        for (int off = 32; off; off >>= 1) acc += __shfl_xor(acc, off, 64);
        if (ln == 0) {
            float o = fminf(fmaxf(acc, LO_C), HI_C);
            out_logits[(size_t)b * (S_DIM + 1) + s + 1] = o;
            float sg = 1.0f / (1.0f + expf(-o));
            coef[b] = LR_C * (sg - target[b]);
        }
    }
    __syncthreads();

    // phase 2: stream all 16 rows; one full row (256 float4) per iteration
    float4* DS = (float4*)(new_weights + (size_t)s * NWROWS * I_DIM);
    #pragma unroll 2
    for (int k = 0; k < NWROWS; ++k) {
        const int b = lastb[k];
        const float4* wr = WS + k * (I_DIM / 4);
        float4* dst = DS + k * (I_DIM / 4);
        if (b < 0) {
            dst[t] = wr[t];
        } else {
            const float c = coef[b];
            const float4* lg = (const float4*)(logit + (size_t)b * I_DIM);
            float4 w4 = wr[t];
            float4 a  = lg[t];
            float4 r;
            r.x = fminf(fmaxf(w4.x - c * a.x, -WC_C), WC_C);
            r.y = fminf(fmaxf(w4.y - c * a.y, -WC_C), WC_C);
            r.z = fminf(fmaxf(w4.z - c * a.z, -WC_C), WC_C);
            r.w = fminf(fmaxf(w4.w - c * a.w, -WC_C), WC_C);
            dst[t] = r;
        }
    }
}

extern "C" void kernel_launch(void* const* d_in, const int* in_sizes, int n_in,
                              void* d_out, int out_size, void* d_ws, size_t ws_size,
                              hipStream_t stream) {
    const float* logit   = (const float*)d_in[0];   // [B, I, 1]
    const float* context = (const float*)d_in[1];   // [B, CTX]
    const float* target  = (const float*)d_in[2];   // [B, 1]
    const float* cm      = (const float*)d_in[3];   // [1, S, 4, CTX]
    const float* cb      = (const float*)d_in[4];   // [1, S, 4, 1]
    const float* weights = (const float*)d_in[5];   // [1, S, 16, I]
    const float* bias    = (const float*)d_in[6];   // [1]

    float* out_logits  = (float*)d_out;                       // [B, S+1]
    float* new_weights = out_logits + (size_t)B_DIM * (S_DIM + 1);

    float4* ctxT4 = (float4*)d_ws;                            // [196][64] float4
    int*    idx_g = (int*)((char*)d_ws + (size_t)CTX4 * B_DIM * sizeof(float4));

    prep_kernel<<<CTX4 * B_DIM / 256, 256, 0, stream>>>(context, bias, ctxT4, out_logits);
    gln_idx_kernel<<<S_DIM, 256, 0, stream>>>(cm, cb, ctxT4, idx_g);
    gln_main2_kernel<<<S_DIM, 256, 0, stream>>>(logit, target, weights, idx_g,
                                                out_logits, new_weights);
}

// Round 3
// 67.168 us; speedup vs baseline: 1.0625x; 1.0261x over previous
//
#include <hip/hip_runtime.h>
#include <math.h>

typedef unsigned long long u64;

#define S_DIM 1023
#define B_DIM 64
#define I_DIM 1024
#define CTX_DIM 784
#define CTX4 196          // CTX_DIM / 4
#define NWROWS 16         // 2^M buckets

#define LR_C 0.01f
#define WC_C 5.0f
#define LO_C (-6.906754778648554f)
#define HI_C ( 6.906754778648554f)

// ---------------- kernel A: context -> float4-transposed layout + bias row ----------------
__global__ __launch_bounds__(256) void prep_kernel(
    const float* __restrict__ context,   // [B, CTX]
    const float* __restrict__ bias,      // [1]
    float4* __restrict__ ctxT4,          // [CTX4][B]
    float* __restrict__ out_logits)      // [B, S+1]
{
    int g = blockIdx.x * 256 + threadIdx.x;      // 0 .. 196*64-1
    int k4 = g >> 6;
    int b  = g & 63;
    ctxT4[g] = *(const float4*)(context + (size_t)b * CTX_DIM + k4 * 4);
    if (g < B_DIM) out_logits[(size_t)g * (S_DIM + 1)] = bias[0];
}

// ---------------- kernel B: halfspace hash -> per-(s,k) membership masks ----------------
__global__ __launch_bounds__(256) void gln_idx_kernel(
    const float* __restrict__ cm,        // [S, 4, CTX]
    const float* __restrict__ cb,        // [S, 4]
    const float4* __restrict__ ctxT4,    // [CTX4][B]
    u64* __restrict__ mask_g)            // [S, 16] bucket membership bitmasks over b
{
    __shared__ float4 cm4[4 * CTX4];     // 12544 B
    __shared__ float  red[4][4][64];     // [q][m][b]
    __shared__ int    bits[4][64];
    __shared__ float  cb_lds[4];

    const int s = blockIdx.x;
    const int t = threadIdx.x;

    const float4* src = (const float4*)(cm + (size_t)s * 4 * CTX_DIM);
    for (int j = t; j < 4 * CTX4; j += 256) cm4[j] = src[j];
    if (t < 4) cb_lds[t] = cb[s * 4 + t];
    __syncthreads();

    const int b = t & 63;
    const int q = t >> 6;          // k-quarter
    float a0 = 0.f, a1 = 0.f, a2 = 0.f, a3 = 0.f;
    const int k0 = q * 49;
    #pragma unroll 7
    for (int kk = 0; kk < 49; ++kk) {
        int k4 = k0 + kk;
        float4 c4 = ctxT4[k4 * 64 + b];          // 16B/lane coalesced
        float4 m0 = cm4[k4];                     // wave-uniform -> LDS broadcast
        float4 m1 = cm4[CTX4 + k4];
        float4 m2 = cm4[2 * CTX4 + k4];
        float4 m3 = cm4[3 * CTX4 + k4];
        a0 += m0.x * c4.x + m0.y * c4.y + m0.z * c4.z + m0.w * c4.w;
        a1 += m1.x * c4.x + m1.y * c4.y + m1.z * c4.z + m1.w * c4.w;
        a2 += m2.x * c4.x + m2.y * c4.y + m2.z * c4.z + m2.w * c4.w;
        a3 += m3.x * c4.x + m3.y * c4.y + m3.z * c4.z + m3.w * c4.w;
    }
    red[q][0][b] = a0;
    red[q][1][b] = a1;
    red[q][2][b] = a2;
    red[q][3][b] = a3;
    __syncthreads();

    {
        int m = t >> 6, bb = t & 63;
        float sum = red[0][m][bb] + red[1][m][bb] + red[2][m][bb] + red[3][m][bb];
        bits[m][bb] = (sum > cb_lds[m]) ? 1 : 0;
    }
    __syncthreads();

    if (t < B_DIM) {   // wave 0 only: lane b
        int v = bits[0][t] + 2 * bits[1][t] + 4 * bits[2][t] + 8 * bits[3][t];
        u64 my = 0;
        #pragma unroll
        for (int kk = 0; kk < NWROWS; ++kk) {
            u64 mk = __ballot(v == kk);
            if (t == kk) my = mk;
        }
        if (t < NWROWS) mask_g[s * NWROWS + t] = my;
    }
}

// ---------------- kernel C: one wave per (s,k) weight row ----------------
__global__ __launch_bounds__(256) void gln_row_kernel(
    const float* __restrict__ logit,     // [B, I]
    const float* __restrict__ target,    // [B]
    const float* __restrict__ weights,   // [S, 16, I]
    const u64*   __restrict__ mask_g,    // [S, 16]
    float* __restrict__ out_logits,      // [B, S+1]
    float* __restrict__ new_weights)     // [S, 16, I]
{
    const int task = blockIdx.x * 4 + (threadIdx.x >> 6);  // s*16 + k
    const int ln   = threadIdx.x & 63;
    const int s    = task >> 4;

    // W row -> registers (issued immediately, 4 float4 in flight)
    const float4* wr = (const float4*)weights + (size_t)task * 256;
    float4 w0 = wr[ln], w1 = wr[ln + 64], w2 = wr[ln + 128], w3 = wr[ln + 192];

    const u64 mask = mask_g[task];
    const int lastb = mask ? (63 - __clzll(mask)) : -1;

    float c = 0.f;
    float4 s0 = {0,0,0,0}, s1 = {0,0,0,0}, s2 = {0,0,0,0}, s3 = {0,0,0,0};

    u64 m = mask;
    while (m) {
        const int b = __builtin_ctzll(m);
        m &= m - 1;
        const float4* lg = (const float4*)logit + (size_t)b * 256;
        float4 a0 = lg[ln], a1 = lg[ln + 64], a2 = lg[ln + 128], a3 = lg[ln + 192];
        float acc = a0.x * w0.x + a0.y * w0.y + a0.z * w0.z + a0.w * w0.w
                  + a1.x * w1.x + a1.y * w1.y + a1.z * w1.z + a1.w * w1.w
                  + a2.x * w2.x + a2.y * w2.y + a2.z * w2.z + a2.w * w2.w
                  + a3.x * w3.x + a3.y * w3.y + a3.z * w3.z + a3.w * w3.w;
        #pragma unroll
        for (int off = 32; off; off >>= 1) acc += __shfl_xor(acc, off, 64);
        float o = fminf(fmaxf(acc, LO_C), HI_C);
        if (ln == 0) out_logits[(size_t)b * (S_DIM + 1) + s + 1] = o;
        float sg = 1.0f / (1.0f + expf(-o));
        float cc = LR_C * (sg - target[b]);
        if (b == lastb) { c = cc; s0 = a0; s1 = a1; s2 = a2; s3 = a3; }
    }

    float4* dst = (float4*)new_weights + (size_t)task * 256;
    if (lastb < 0) {            // untouched row: verbatim copy (no clip!)
        dst[ln]       = w0;
        dst[ln + 64]  = w1;
        dst[ln + 128] = w2;
        dst[ln + 192] = w3;
    } else {
        float4 r0, r1, r2, r3;
        r0.x = fminf(fmaxf(w0.x - c * s0.x, -WC_C), WC_C);
        r0.y = fminf(fmaxf(w0.y - c * s0.y, -WC_C), WC_C);
        r0.z = fminf(fmaxf(w0.z - c * s0.z, -WC_C), WC_C);
        r0.w = fminf(fmaxf(w0.w - c * s0.w, -WC_C), WC_C);
        r1.x = fminf(fmaxf(w1.x - c * s1.x, -WC_C), WC_C);
        r1.y = fminf(fmaxf(w1.y - c * s1.y, -WC_C), WC_C);
        r1.z = fminf(fmaxf(w1.z - c * s1.z, -WC_C), WC_C);
        r1.w = fminf(fmaxf(w1.w - c * s1.w, -WC_C), WC_C);
        r2.x = fminf(fmaxf(w2.x - c * s2.x, -WC_C), WC_C);
        r2.y = fminf(fmaxf(w2.y - c * s2.y, -WC_C), WC_C);
        r2.z = fminf(fmaxf(w2.z - c * s2.z, -WC_C), WC_C);
        r2.w = fminf(fmaxf(w2.w - c * s2.w, -WC_C), WC_C);
        r3.x = fminf(fmaxf(w3.x - c * s3.x, -WC_C), WC_C);
        r3.y = fminf(fmaxf(w3.y - c * s3.y, -WC_C), WC_C);
        r3.z = fminf(fmaxf(w3.z - c * s3.z, -WC_C), WC_C);
        r3.w = fminf(fmaxf(w3.w - c * s3.w, -WC_C), WC_C);
        dst[ln]       = r0;
        dst[ln + 64]  = r1;
        dst[ln + 128] = r2;
        dst[ln + 192] = r3;
    }
}

extern "C" void kernel_launch(void* const* d_in, const int* in_sizes, int n_in,
                              void* d_out, int out_size, void* d_ws, size_t ws_size,
                              hipStream_t stream) {
    const float* logit   = (const float*)d_in[0];   // [B, I, 1]
    const float* context = (const float*)d_in[1];   // [B, CTX]
    const float* target  = (const float*)d_in[2];   // [B, 1]
    const float* cm      = (const float*)d_in[3];   // [1, S, 4, CTX]
    const float* cb      = (const float*)d_in[4];   // [1, S, 4, 1]
    const float* weights = (const float*)d_in[5];   // [1, S, 16, I]
    const float* bias    = (const float*)d_in[6];   // [1]

    float* out_logits  = (float*)d_out;                       // [B, S+1]
    float* new_weights = out_logits + (size_t)B_DIM * (S_DIM + 1);

    float4* ctxT4 = (float4*)d_ws;                            // [196][64] float4 (200704 B)
    u64*    mask_g = (u64*)((char*)d_ws + (size_t)CTX4 * B_DIM * sizeof(float4));

    prep_kernel<<<CTX4 * B_DIM / 256, 256, 0, stream>>>(context, bias, ctxT4, out_logits);
    gln_idx_kernel<<<S_DIM, 256, 0, stream>>>(cm, cb, ctxT4, mask_g);
    gln_row_kernel<<<S_DIM * NWROWS / 4, 256, 0, stream>>>(logit, target, weights, mask_g,
                                                           out_logits, new_weights);
}